// Round 19
// baseline (40.502 us; speedup 1.0000x reference)
//
#include <hip/hip_runtime.h>
#include <math.h>

#define HH 192
#define WW 192
#define NPIX (HH * WW)
#define SCALE 0.25f            // head_dim(16)^-0.5
#define C1 0.36067376f         // SCALE * log2(e)

// attention tile: 4 rows x 8 cols; halo 10 rows x 14 cols, cols padded to 16
#define HR 10
#define HC 14
#define NSLOT 160              // 10 * 16 n-slots (pads cx=14,15 are masked)
#define VOFF 160               // dword offset of V region (mC first)
#define AOFF 5280              // dword offset of A-tile region (after V)

typedef __attribute__((ext_vector_type(8))) _Float16 f16x8;
typedef __attribute__((ext_vector_type(4))) _Float16 f16x4;
typedef __attribute__((ext_vector_type(4))) float f32x4;

#if __has_builtin(__builtin_amdgcn_exp2f)
#define EXP2(x) __builtin_amdgcn_exp2f(x)
#else
#define EXP2(x) exp2f(x)
#endif

#define MFMA16(a, b, c) __builtin_amdgcn_mfma_f32_16x16x16f16((a), (b), (c), 0, 0, 0)

static __device__ __forceinline__ short f16s(float f)
{
    _Float16 h = (_Float16)f;
    short s; __builtin_memcpy(&s, &h, 2); return s;
}

static __device__ __forceinline__ unsigned int pack_f16(float a, float b)
{
    unsigned short ul = (unsigned short)f16s(a);
    unsigned short uh = (unsigned short)f16s(b);
    return ((unsigned int)uh << 16) | ul;
}

// ---------------------------------------------------------------------------
// Kernel 1: Q/K/V projection via MFMA — 128 px/block, VECTORIZED staging:
// x and weights read as float4 (80 -> 20 global loads per thread; staging
// was issue/latency-bound, not BW-bound). LDS 46 KB -> 3 blocks/CU,
// 289 blocks single-round. Each wave does 2 M-tiles sequentially.
// Tail block (blockIdx == NPIX/128) preps wp into wT rows 192..255.
// ---------------------------------------------------------------------------
__global__ __launch_bounds__(256) void qkv_mfma(
    const float* __restrict__ x,
    const float* __restrict__ wq, const float* __restrict__ wk,
    const float* __restrict__ wv, const float* __restrict__ wp,
    unsigned int* __restrict__ qg, unsigned int* __restrict__ kg,
    unsigned int* __restrict__ vg, short* __restrict__ wT)
{
    const int t = threadIdx.x;

    if (blockIdx.x == NPIX / 128) {
        #pragma unroll
        for (int i = 0; i < 4; ++i) {
            const int idx = i * 256 + t;      // 0..1023
            const int k = idx >> 4, n4 = idx & 15;
            const float4 wv4 = *reinterpret_cast<const float4*>(wp + k * 64 + n4 * 4);
            const float we[4] = { wv4.x, wv4.y, wv4.z, wv4.w };
            #pragma unroll
            for (int e = 0; e < 4; ++e)
                wT[(192 + n4 * 4 + e) * 64 + k] = f16s(we[e]);
        }
        return;
    }

    __shared__ short lds[(128 + 192) * 72];  // xT[128][72] then wTs[192][72]
    short* xT = lds;
    short* wTs = lds + 128 * 72;
    const int px0 = blockIdx.x * 128;

    // stage xT: 128 px x 64 cin as float4 (4 px per load, coalesced)
    #pragma unroll
    for (int r = 0; r < 8; ++r) {
        const int idx = r * 256 + t;          // 0..2047
        const int cin = idx >> 5;             // 32 float4 per cin row
        const int p4 = idx & 31;
        const float4 xv = *reinterpret_cast<const float4*>(
            x + (size_t)cin * NPIX + px0 + p4 * 4);
        const float xe[4] = { xv.x, xv.y, xv.z, xv.w };
        #pragma unroll
        for (int e = 0; e < 4; ++e)
            xT[(p4 * 4 + e) * 72 + cin] = f16s(xe[e]);
    }
    // stage wTs for q,k,v: float4 along n (coalesced), transpose into LDS
    #pragma unroll
    for (int m = 0; m < 3; ++m) {
        const float* ws = (m == 0) ? wq : (m == 1) ? wk : wv;
        #pragma unroll
        for (int r = 0; r < 4; ++r) {
            const int idx = r * 256 + t;      // 0..1023
            const int k = idx >> 4, n4 = idx & 15;
            const float4 wv4 = *reinterpret_cast<const float4*>(ws + k * 64 + n4 * 4);
            const float we[4] = { wv4.x, wv4.y, wv4.z, wv4.w };
            #pragma unroll
            for (int e = 0; e < 4; ++e)
                wTs[(m * 64 + n4 * 4 + e) * 72 + k] = f16s(we[e]);
        }
    }
    __syncthreads();

    const int lane = t & 63;
    const int wid  = t >> 6;
    const int l15  = lane & 15;
    const int kg4  = lane >> 4;

    // each wave: M-tiles wid and wid+4
    #pragma unroll
    for (int mtile = 0; mtile < 2; ++mtile) {
        const int m = wid + mtile * 4;

        f32x4 acc[12];
        #pragma unroll
        for (int nt = 0; nt < 12; ++nt) acc[nt] = (f32x4){0.f, 0.f, 0.f, 0.f};

        #pragma unroll
        for (int ks = 0; ks < 2; ++ks) {
            const f16x8 a = *reinterpret_cast<const f16x8*>(
                &xT[(m * 16 + l15) * 72 + ks * 32 + kg4 * 8]);
            #pragma unroll
            for (int nt = 0; nt < 12; ++nt) {
                const f16x8 b = *reinterpret_cast<const f16x8*>(
                    &wTs[(nt * 16 + l15) * 72 + ks * 32 + kg4 * 8]);
                acc[nt] = __builtin_amdgcn_mfma_f32_16x16x32_f16(a, b, acc[nt], 0, 0, 0);
            }
        }

        #pragma unroll
        for (int nt = 0; nt < 12; ++nt) {
            unsigned int* dst = (nt < 4) ? qg : (nt < 8) ? kg : vg;
            const int dwb = (nt & 3) * 8 + (l15 >> 1);
            #pragma unroll
            for (int r = 0; r < 4; ++r) {
                const float val = acc[nt][r];
                const float par = __shfl_xor(val, 1, 64);
                if (!(lane & 1)) {
                    const int opx = px0 + m * 16 + kg4 * 4 + r;
                    dst[(size_t)opx * 32 + dwb] = pack_f16(val, par);
                }
            }
        }
    }
}

// ---------------------------------------------------------------------------
// Kernel 2: MFMA neighborhood attention + fused MFMA output projection.
// EXACT r16/r18 structure (proven 36.5): 4 waves, wave = head, both q-tiles
// per wave, no pre-staging prefetch, per-nt fused QK->softmax->PV,
// dedicated A-region. LDS: mC[160] + V[5120] + A[1152] dw = 25.7 KB.
// ---------------------------------------------------------------------------
__global__ __launch_bounds__(256) void attn_proj(
    const unsigned int* __restrict__ qg,
    const unsigned int* __restrict__ kg,
    const unsigned int* __restrict__ vg,
    const float* __restrict__ sims,
    const short* __restrict__ wT,
    float* __restrict__ out)
{
    __shared__ unsigned int smem[AOFF + 1152];    // mC | V | A

    const int bid = blockIdx.x;
    const int tl = (bid & 7) * 144 + (bid >> 3);  // XCD swizzle (1152 = 8*144)
    const int ty = tl / 24, tx = tl - ty * 24;    // 48 x 24 tiles
    const int Y0 = ty * 4, X0 = tx * 8;
    int hy0 = Y0 - 3; hy0 = hy0 < 0 ? 0 : (hy0 > HH - HR ? HH - HR : hy0);
    int hx0 = X0 - 3; hx0 = hx0 < 0 ? 0 : (hx0 > WW - HC ? WW - HC : hx0);
    const int t = threadIdx.x;

    // ---- stage V (row-major [n][16] f16 per head, zero-filled pads) + mC
    #pragma unroll
    for (int i = 0; i < 5; ++i) {
        const int idx = i * 256 + t;              // 0..1279
        const int n = idx >> 3, u = idx & 7;
        const int ry = n >> 4, cx = n & 15;
        uint4 vv = make_uint4(0u, 0u, 0u, 0u);
        if (cx < HC) {
            const int np = (hy0 + ry) * WW + hx0 + cx;
            vv = *reinterpret_cast<const uint4*>(vg + (size_t)np * 32 + u * 4);
        }
        const int h = u >> 1, hf = u & 1;
        *reinterpret_cast<uint4*>(smem + VOFF + h * 1280 + n * 8 + hf * 4) = vv;
    }
    if (t < NSLOT) {
        const int ry = t >> 4, cx = t & 15;
        float m = 0.f;
        if (cx < HC) {
            const int np = (hy0 + ry) * WW + hx0 + cx;
            const int sbase = (Y0 >> 4) * 12 + (X0 >> 4);   // block-uniform
            m = sims[np * 144 + sbase];
        }
        reinterpret_cast<float*>(smem)[t] = m * C1;
    }
    __syncthreads();

    const int h    = t >> 6;                  // wave = head
    const int lane = t & 63;
    const int l15  = lane & 15;
    const int kg4  = lane >> 4;
    const float* mC = reinterpret_cast<const float*>(smem);

    // ---- V^T A-fragments via hardware transpose read (linear 8B/lane)
    const unsigned vbyte = (unsigned)(uintptr_t)smem + VOFF * 4
                         + h * 5120 + lane * 8;
    f16x4 vf[10];
#define TRREAD(I, IMM) \
    asm volatile("ds_read_b64_tr_b16 %0, %1 offset:" IMM \
                 : "=v"(vf[I]) : "v"(vbyte))
    TRREAD(0, "0");    TRREAD(1, "512");  TRREAD(2, "1024"); TRREAD(3, "1536");
    TRREAD(4, "2048"); TRREAD(5, "2560"); TRREAD(6, "3072"); TRREAD(7, "3584");
    TRREAD(8, "4096"); TRREAD(9, "4608");
#undef TRREAD

    // ---- K A-fragments (qt-invariant): lane col cx = l15 of halo row nt
    const unsigned int* kgp = kg + (size_t)(hy0 * WW + hx0 + l15) * 32
                            + h * 8 + kg4 * 2;
    f16x4 kf[10];
    #pragma unroll
    for (int nt = 0; nt < 10; ++nt)
        kf[nt] = *reinterpret_cast<const f16x4*>(kgp + (size_t)nt * (WW * 32));

    // tr-reads must land before PV; single wait, then both qt passes
    asm volatile("s_waitcnt lgkmcnt(0)" ::: "memory");
    __builtin_amdgcn_sched_barrier(0);

    short* A = reinterpret_cast<short*>(smem + AOFF);

    #pragma unroll 1
    for (int qt = 0; qt < 2; ++qt) {
        const int q = qt * 16 + l15;
        const int qry = q >> 3, qcx = q & 7;
        const int y = Y0 + qry, x = X0 + qcx;
        int sy = y - 3; sy = sy < 0 ? 0 : (sy > HH - 7 ? HH - 7 : sy);
        int sx = x - 3; sx = sx < 0 ? 0 : (sx > WW - 7 ? WW - 7 : sx);
        const int wy = sy - hy0, wx = sx - hx0;

        // Q^T B-fragment from global (lane col q, k-rows d = kg4*4..+3)
        const f16x4 qb = *reinterpret_cast<const f16x4*>(
            qg + (size_t)(y * WW + x) * 32 + h * 8 + kg4 * 2);

        // masks for D rows (cx = kg4*4 + e)
        float vx[4];
        #pragma unroll
        for (int rr = 0; rr < 4; ++rr)
            vx[rr] = ((unsigned)(kg4 * 4 + rr - wx) < 7u) ? 1.f : 0.f;

        // per-nt fused QK^T -> softmax -> PV (no-max softmax; logits bounded)
        float Ss = 0.f;
        f32x4 o = (f32x4){0.f, 0.f, 0.f, 0.f};
        #pragma unroll
        for (int nt = 0; nt < 10; ++nt) {
            const f32x4 s = MFMA16(kf[nt], qb, ((f32x4){0.f, 0.f, 0.f, 0.f}));
            const f32x4 mcv = *reinterpret_cast<const f32x4*>(
                mC + nt * 16 + kg4 * 4);
            const float vy = ((unsigned)(nt - wy) < 7u) ? 1.f : 0.f;
            float pf[4];
            #pragma unroll
            for (int e = 0; e < 4; ++e) {
                const float u = s[e] * mcv[e];       // dot * m * SCALE*log2e
                const float p = EXP2(u);
                const float pv = p * vy * vx[e];
                Ss += pv;
                pf[e] = pv * mcv[e];                 // P^T = pv * m * C1
            }
            const f16x4 pt = (f16x4){(_Float16)pf[0], (_Float16)pf[1],
                                     (_Float16)pf[2], (_Float16)pf[3]};
            o = MFMA16(vf[nt], pt, o);
        }
        Ss += __shfl_xor(Ss, 16, 64);
        Ss += __shfl_xor(Ss, 32, 64);
        const float invq = 1.f / (C1 * Ss);

        // immediate A-tile store (A region does NOT alias mC/V)
        const f16x4 ov = (f16x4){
            (_Float16)(o[0] * invq), (_Float16)(o[1] * invq),
            (_Float16)(o[2] * invq), (_Float16)(o[3] * invq)};
        *reinterpret_cast<f16x4*>(&A[q * 72 + h * 16 + kg4 * 4]) = ov;
    }
    __syncthreads();

    // ---- fused projection: A_lds (f16 [32 q][72 ch]) x wp via MFMA
    const short* A_lds = reinterpret_cast<const short*>(smem + AOFF);
    const int mt  = h & 1;                    // M-tile (16 px)
    const int np2 = h >> 1;                   // N-pair (2 x 16 couts)

    f16x8 afrag[2];
    #pragma unroll
    for (int ks = 0; ks < 2; ++ks)
        afrag[ks] = *reinterpret_cast<const f16x8*>(
            &A_lds[(mt * 16 + l15) * 72 + ks * 32 + kg4 * 8]);

    #pragma unroll
    for (int nt2 = 0; nt2 < 2; ++nt2) {
        const int n = (np2 * 2 + nt2) * 16 + l15;
        f32x4 pacc = (f32x4){0.f, 0.f, 0.f, 0.f};
        #pragma unroll
        for (int ks = 0; ks < 2; ++ks) {
            const f16x8 b = *reinterpret_cast<const f16x8*>(
                &wT[(192 + n) * 64 + ks * 32 + kg4 * 8]);
            pacc = __builtin_amdgcn_mfma_f32_16x16x32_f16(afrag[ks], b, pacc, 0, 0, 0);
        }
        const int pr = mt * 16 + kg4 * 4;     // 4 consecutive tile pixels
        const int gy = Y0 + (pr >> 3), gx = X0 + (pr & 7);
        *reinterpret_cast<float4*>(out + (size_t)n * NPIX + gy * WW + gx) =
            make_float4(pacc[0], pacc[1], pacc[2], pacc[3]);
    }
}

// ---------------------------------------------------------------------------
extern "C" void kernel_launch(void* const* d_in, const int* in_sizes, int n_in,
                              void* d_out, int out_size, void* d_ws, size_t ws_size,
                              hipStream_t stream)
{
    const float* x    = (const float*)d_in[0];
    const float* sims = (const float*)d_in[1];
    const float* wq   = (const float*)d_in[2];
    const float* wk   = (const float*)d_in[3];
    const float* wv   = (const float*)d_in[4];
    const float* wp   = (const float*)d_in[5];
    float* out = (float*)d_out;

    unsigned int* qg = (unsigned int*)d_ws;            // f16x2 [NPIX][32]
    unsigned int* kg = qg + (size_t)NPIX * 32;
    unsigned int* vg = kg + (size_t)NPIX * 32;
    short* wT = (short*)(vg + (size_t)NPIX * 32);      // f16 [256][64]

    qkv_mfma<<<NPIX / 128 + 1, 256, 0, stream>>>(x, wq, wk, wv, wp, qg, kg, vg, wT);
    attn_proj<<<1152, 256, 0, stream>>>(qg, kg, vg, sims, wT, out);
}

// Round 20
// 35.691 us; speedup vs baseline: 1.1348x; 1.1348x over previous
//
#include <hip/hip_runtime.h>
#include <math.h>

#define HH 192
#define WW 192
#define NPIX (HH * WW)
#define SCALE 0.25f            // head_dim(16)^-0.5
#define C1 0.36067376f         // SCALE * log2(e)

// attention tile: 4 rows x 8 cols; halo 10 rows x 14 cols, cols padded to 16
#define HR 10
#define HC 14
#define NSLOT 160              // 10 * 16 n-slots (pads cx=14,15 are masked)
#define VOFF 160               // dword offset of V region (mC first)
#define AOFF 5280              // dword offset of A-tile region (after V)

typedef __attribute__((ext_vector_type(8))) _Float16 f16x8;
typedef __attribute__((ext_vector_type(4))) _Float16 f16x4;
typedef __attribute__((ext_vector_type(4))) float f32x4;

#if __has_builtin(__builtin_amdgcn_exp2f)
#define EXP2(x) __builtin_amdgcn_exp2f(x)
#else
#define EXP2(x) exp2f(x)
#endif

#define MFMA16(a, b, c) __builtin_amdgcn_mfma_f32_16x16x16f16((a), (b), (c), 0, 0, 0)

static __device__ __forceinline__ short f16s(float f)
{
    _Float16 h = (_Float16)f;
    short s; __builtin_memcpy(&s, &h, 2); return s;
}

static __device__ __forceinline__ unsigned int pack_f16(float a, float b)
{
    unsigned short ul = (unsigned short)f16s(a);
    unsigned short uh = (unsigned short)f16s(b);
    return ((unsigned int)uh << 16) | ul;
}

// ---------------------------------------------------------------------------
// Kernel 1: Q/K/V projection via MFMA (r16-champion version, 64 px/block,
// scalar staging — r19 proved float4 staging causes 32-way LDS write
// conflicts). Tail block preps wp into wT rows 192..255.
// ---------------------------------------------------------------------------
__global__ __launch_bounds__(256) void qkv_mfma(
    const float* __restrict__ x,
    const float* __restrict__ wq, const float* __restrict__ wk,
    const float* __restrict__ wv, const float* __restrict__ wp,
    unsigned int* __restrict__ qg, unsigned int* __restrict__ kg,
    unsigned int* __restrict__ vg, short* __restrict__ wT)
{
    const int t = threadIdx.x;

    if (blockIdx.x == NPIX / 64) {
        #pragma unroll
        for (int i = 0; i < 16; ++i) {
            const int idx = i * 256 + t;      // 0..4095
            const int n = idx >> 6, k = idx & 63;
            wT[(192 + n) * 64 + k] = f16s(wp[k * 64 + n]);
        }
        return;
    }

    __shared__ short lds[(64 + 192) * 72];   // xT then wTs
    short* xT = lds;
    short* wTs = lds + 64 * 72;
    const int px0 = blockIdx.x * 64;

    #pragma unroll
    for (int r = 0; r < 16; ++r) {
        const int idx = r * 256 + t;          // 0..4095
        const int cin = idx >> 6, pxl = idx & 63;
        xT[pxl * 72 + cin] = f16s(x[(size_t)cin * NPIX + px0 + pxl]);
    }
    #pragma unroll
    for (int m = 0; m < 3; ++m) {
        const float* ws = (m == 0) ? wq : (m == 1) ? wk : wv;
        #pragma unroll
        for (int r = 0; r < 16; ++r) {
            const int idx = r * 256 + t;      // 0..4095
            const int k = idx >> 6, n = idx & 63;
            wTs[(m * 64 + n) * 72 + k] = f16s(ws[k * 64 + n]);
        }
    }
    __syncthreads();

    const int lane = t & 63;
    const int wid  = t >> 6;                  // M-tile (16 px)
    const int l15  = lane & 15;
    const int kg4  = lane >> 4;

    f32x4 acc[12];
    #pragma unroll
    for (int nt = 0; nt < 12; ++nt) acc[nt] = (f32x4){0.f, 0.f, 0.f, 0.f};

    #pragma unroll
    for (int ks = 0; ks < 2; ++ks) {
        const f16x8 a = *reinterpret_cast<const f16x8*>(
            &xT[(wid * 16 + l15) * 72 + ks * 32 + kg4 * 8]);
        #pragma unroll
        for (int nt = 0; nt < 12; ++nt) {
            const f16x8 b = *reinterpret_cast<const f16x8*>(
                &wTs[(nt * 16 + l15) * 72 + ks * 32 + kg4 * 8]);
            acc[nt] = __builtin_amdgcn_mfma_f32_16x16x32_f16(a, b, acc[nt], 0, 0, 0);
        }
    }

    #pragma unroll
    for (int nt = 0; nt < 12; ++nt) {
        unsigned int* dst = (nt < 4) ? qg : (nt < 8) ? kg : vg;
        const int dwb = (nt & 3) * 8 + (l15 >> 1);
        #pragma unroll
        for (int r = 0; r < 4; ++r) {
            const float val = acc[nt][r];
            const float par = __shfl_xor(val, 1, 64);
            if (!(lane & 1)) {
                const int opx = px0 + wid * 16 + kg4 * 4 + r;
                dst[(size_t)opx * 32 + dwb] = pack_f16(val, par);
            }
        }
    }
}

// ---------------------------------------------------------------------------
// Kernel 2: MFMA neighborhood attention + fused MFMA output projection.
// r16 structure (proven 36.5): 4 waves, wave = head, both q-tiles per wave,
// per-nt fused QK->softmax->PV, dedicated A-region.
// CHANGE vs r16: proj MFMA operands SWAPPED (A = wp^T, B = attn-out^T) so
// D col = pixel -> coalesced scalar stores (8 x 32B segments per store)
// instead of 64-way-scattered float4 stores. Same bytes read, same values.
// LDS: mC[160] + V[5120] + A[1152] dw = 25.7 KB.
// ---------------------------------------------------------------------------
__global__ __launch_bounds__(256) void attn_proj(
    const unsigned int* __restrict__ qg,
    const unsigned int* __restrict__ kg,
    const unsigned int* __restrict__ vg,
    const float* __restrict__ sims,
    const short* __restrict__ wT,
    float* __restrict__ out)
{
    __shared__ unsigned int smem[AOFF + 1152];    // mC | V | A

    const int bid = blockIdx.x;
    const int tl = (bid & 7) * 144 + (bid >> 3);  // XCD swizzle (1152 = 8*144)
    const int ty = tl / 24, tx = tl - ty * 24;    // 48 x 24 tiles
    const int Y0 = ty * 4, X0 = tx * 8;
    int hy0 = Y0 - 3; hy0 = hy0 < 0 ? 0 : (hy0 > HH - HR ? HH - HR : hy0);
    int hx0 = X0 - 3; hx0 = hx0 < 0 ? 0 : (hx0 > WW - HC ? WW - HC : hx0);
    const int t = threadIdx.x;

    // ---- stage V (row-major [n][16] f16 per head, zero-filled pads) + mC
    #pragma unroll
    for (int i = 0; i < 5; ++i) {
        const int idx = i * 256 + t;              // 0..1279
        const int n = idx >> 3, u = idx & 7;
        const int ry = n >> 4, cx = n & 15;
        uint4 vv = make_uint4(0u, 0u, 0u, 0u);
        if (cx < HC) {
            const int np = (hy0 + ry) * WW + hx0 + cx;
            vv = *reinterpret_cast<const uint4*>(vg + (size_t)np * 32 + u * 4);
        }
        const int h = u >> 1, hf = u & 1;
        *reinterpret_cast<uint4*>(smem + VOFF + h * 1280 + n * 8 + hf * 4) = vv;
    }
    if (t < NSLOT) {
        const int ry = t >> 4, cx = t & 15;
        float m = 0.f;
        if (cx < HC) {
            const int np = (hy0 + ry) * WW + hx0 + cx;
            const int sbase = (Y0 >> 4) * 12 + (X0 >> 4);   // block-uniform
            m = sims[np * 144 + sbase];
        }
        reinterpret_cast<float*>(smem)[t] = m * C1;
    }
    __syncthreads();

    const int h    = t >> 6;                  // wave = head
    const int lane = t & 63;
    const int l15  = lane & 15;
    const int kg4  = lane >> 4;
    const float* mC = reinterpret_cast<const float*>(smem);

    // ---- V^T A-fragments via hardware transpose read (linear 8B/lane)
    const unsigned vbyte = (unsigned)(uintptr_t)smem + VOFF * 4
                         + h * 5120 + lane * 8;
    f16x4 vf[10];
#define TRREAD(I, IMM) \
    asm volatile("ds_read_b64_tr_b16 %0, %1 offset:" IMM \
                 : "=v"(vf[I]) : "v"(vbyte))
    TRREAD(0, "0");    TRREAD(1, "512");  TRREAD(2, "1024"); TRREAD(3, "1536");
    TRREAD(4, "2048"); TRREAD(5, "2560"); TRREAD(6, "3072"); TRREAD(7, "3584");
    TRREAD(8, "4096"); TRREAD(9, "4608");
#undef TRREAD

    // ---- K A-fragments (qt-invariant): lane col cx = l15 of halo row nt
    const unsigned int* kgp = kg + (size_t)(hy0 * WW + hx0 + l15) * 32
                            + h * 8 + kg4 * 2;
    f16x4 kf[10];
    #pragma unroll
    for (int nt = 0; nt < 10; ++nt)
        kf[nt] = *reinterpret_cast<const f16x4*>(kgp + (size_t)nt * (WW * 32));

    // tr-reads must land before PV; single wait, then both qt passes
    asm volatile("s_waitcnt lgkmcnt(0)" ::: "memory");
    __builtin_amdgcn_sched_barrier(0);

    short* A = reinterpret_cast<short*>(smem + AOFF);

    #pragma unroll 1
    for (int qt = 0; qt < 2; ++qt) {
        const int q = qt * 16 + l15;
        const int qry = q >> 3, qcx = q & 7;
        const int y = Y0 + qry, x = X0 + qcx;
        int sy = y - 3; sy = sy < 0 ? 0 : (sy > HH - 7 ? HH - 7 : sy);
        int sx = x - 3; sx = sx < 0 ? 0 : (sx > WW - 7 ? WW - 7 : sx);
        const int wy = sy - hy0, wx = sx - hx0;

        // Q^T B-fragment from global (lane col q, k-rows d = kg4*4..+3)
        const f16x4 qb = *reinterpret_cast<const f16x4*>(
            qg + (size_t)(y * WW + x) * 32 + h * 8 + kg4 * 2);

        // masks for D rows (cx = kg4*4 + e)
        float vx[4];
        #pragma unroll
        for (int rr = 0; rr < 4; ++rr)
            vx[rr] = ((unsigned)(kg4 * 4 + rr - wx) < 7u) ? 1.f : 0.f;

        // per-nt fused QK^T -> softmax -> PV (no-max softmax; logits bounded)
        float Ss = 0.f;
        f32x4 o = (f32x4){0.f, 0.f, 0.f, 0.f};
        #pragma unroll
        for (int nt = 0; nt < 10; ++nt) {
            const f32x4 s = MFMA16(kf[nt], qb, ((f32x4){0.f, 0.f, 0.f, 0.f}));
            const f32x4 mcv = *reinterpret_cast<const f32x4*>(
                mC + nt * 16 + kg4 * 4);
            const float vy = ((unsigned)(nt - wy) < 7u) ? 1.f : 0.f;
            float pf[4];
            #pragma unroll
            for (int e = 0; e < 4; ++e) {
                const float u = s[e] * mcv[e];       // dot * m * SCALE*log2e
                const float p = EXP2(u);
                const float pv = p * vy * vx[e];
                Ss += pv;
                pf[e] = pv * mcv[e];                 // P^T = pv * m * C1
            }
            const f16x4 pt = (f16x4){(_Float16)pf[0], (_Float16)pf[1],
                                     (_Float16)pf[2], (_Float16)pf[3]};
            o = MFMA16(vf[nt], pt, o);
        }
        Ss += __shfl_xor(Ss, 16, 64);
        Ss += __shfl_xor(Ss, 32, 64);
        const float invq = 1.f / (C1 * Ss);

        // immediate A-tile store (A region does NOT alias mC/V)
        const f16x4 ov = (f16x4){
            (_Float16)(o[0] * invq), (_Float16)(o[1] * invq),
            (_Float16)(o[2] * invq), (_Float16)(o[3] * invq)};
        *reinterpret_cast<f16x4*>(&A[q * 72 + h * 16 + kg4 * 4]) = ov;
    }
    __syncthreads();

    // ---- fused projection, SWAPPED operands:
    // out^T[c][px] = sum_k wp^T[c][k] * A_att[px][k]
    // A'-frag = wT row (192 + h*16 + l15) (cout-block cb = h);
    // B'-frag = A_lds[px = pxt*16+l15][k]  (same bytes as r16's afrag);
    // D: col = px (l15), row = cout (kg4*4+reg) -> coalesced scalar stores.
    const short* A_lds = reinterpret_cast<const short*>(smem + AOFF);

    f16x8 aw[2];
    #pragma unroll
    for (int ks = 0; ks < 2; ++ks)
        aw[ks] = *reinterpret_cast<const f16x8*>(
            &wT[(192 + h * 16 + l15) * 64 + ks * 32 + kg4 * 8]);

    #pragma unroll
    for (int pxt = 0; pxt < 2; ++pxt) {
        f32x4 pacc = (f32x4){0.f, 0.f, 0.f, 0.f};
        #pragma unroll
        for (int ks = 0; ks < 2; ++ks) {
            const f16x8 bx = *reinterpret_cast<const f16x8*>(
                &A_lds[(pxt * 16 + l15) * 72 + ks * 32 + kg4 * 8]);
            pacc = __builtin_amdgcn_mfma_f32_16x16x32_f16(aw[ks], bx, pacc, 0, 0, 0);
        }
        const int p = pxt * 16 + l15;             // tile pixel (D col)
        const int gy = Y0 + (p >> 3), gx = X0 + (p & 7);
        #pragma unroll
        for (int r = 0; r < 4; ++r) {
            const int c = h * 16 + kg4 * 4 + r;   // cout (D row)
            out[(size_t)c * NPIX + gy * WW + gx] = pacc[r];
        }
    }
}

// ---------------------------------------------------------------------------
extern "C" void kernel_launch(void* const* d_in, const int* in_sizes, int n_in,
                              void* d_out, int out_size, void* d_ws, size_t ws_size,
                              hipStream_t stream)
{
    const float* x    = (const float*)d_in[0];
    const float* sims = (const float*)d_in[1];
    const float* wq   = (const float*)d_in[2];
    const float* wk   = (const float*)d_in[3];
    const float* wv   = (const float*)d_in[4];
    const float* wp   = (const float*)d_in[5];
    float* out = (float*)d_out;

    unsigned int* qg = (unsigned int*)d_ws;            // f16x2 [NPIX][32]
    unsigned int* kg = qg + (size_t)NPIX * 32;
    unsigned int* vg = kg + (size_t)NPIX * 32;
    short* wT = (short*)(vg + (size_t)NPIX * 32);      // f16 [256][64]

    qkv_mfma<<<NPIX / 64 + 1, 256, 0, stream>>>(x, wq, wk, wv, wp, qg, kg, vg, wT);
    attn_proj<<<1152, 256, 0, stream>>>(qg, kg, vg, sims, wT, out);
}